// Round 1
// 856.410 us; speedup vs baseline: 1.0203x; 1.0203x over previous
//
#include <hip/hip_runtime.h>

// CobaLIF SNN forward. B=256, T=1000, F=700, H=256, O=20.
//
// KEY THEOREM (verified by prior-session counters: correction masks always
// empty, absmax 0.0): for t>=1, if z(t-1)=all-ones then v(t) = 30*g_e(t) >=
// 30*rowsum(relu(w_rec)) ~ 270 >> 1, INDEPENDENT of the input drive (which
// only adds >=0). So z == 1 for all t>=1 by induction from z(0), and the
// readout input is constantly csum => voltages are batch-independent.
//   -> spikes: t=0 from exact fp32 drive; t>=1 pure 1.0 fill (262 MB).
//   -> voltages: per-t replay of the 20-channel scalar recurrence
//      (bit-identical fp32 order), broadcast to B.
// Exactness is NOT assumed: per-b flag (any z(0)==0) and global flag
// (min rowsum <= 0.04) gate fallback_k, a full sequential per-b recompute.
// With this data all flags are 0.
//
// R8 restructure: 7 launches -> 4. prep fused; gflag folded into drive0;
// volt scan+fill+spike fill fused into one grid (volt blocks first, hidden
// under the 262 MB store stream). No checked-output arithmetic changed.

#define TT 1000
#define BB 256
#define FF 700
#define HH 256
#define OO 20

// ws layout (bytes), total ~548 KB:
#define WS_WRT   0         // float2 wr2i[HH][HH]: [h'*HH+h] = (relu(W[h][h']), relu(-W[h][h']))
#define WS_RSUM  524288    // float2 rsum[HH]: row sums of (w_rec_e, w_rec_i)
#define WS_WOT   526336    // float woT[HH][OO]: w_out transposed
#define WS_CSUM  546816    // float csum[OO]: column sums of w_out
#define WS_GFLAG 626944    // int: global fallback flag
#define WS_BFLAG 626948    // int[BB]: per-batch fallback flags

// blocks 0..255 (h): wr2i column, rsum[h], woT row h. block 256: csum.
__global__ __launch_bounds__(256) void prep_k(const float* __restrict__ w_rec,
                                              const float* __restrict__ w_out,
                                              float2* __restrict__ wr2i,
                                              float2* __restrict__ rsum,
                                              float* __restrict__ woT,
                                              float* __restrict__ csum) {
    const int blk = blockIdx.x, tid = threadIdx.x;
    __shared__ float red[8];
    if (blk < HH) {
        const int h = blk;
        float w = w_rec[h * HH + tid];                  // coalesced row read
        float e = fmaxf(w, 0.f), ii = fmaxf(-w, 0.f);
        wr2i[tid * HH + h] = make_float2(e, ii);        // scattered (512 KB total, cheap)
        float se = e, si = ii;
        #pragma unroll
        for (int m = 32; m; m >>= 1) {
            se += __shfl_xor(se, m, 64);
            si += __shfl_xor(si, m, 64);
        }
        const int wv = tid >> 6;
        if ((tid & 63) == 0) { red[2 * wv] = se; red[2 * wv + 1] = si; }
        __syncthreads();
        if (tid == 0)
            rsum[h] = make_float2(red[0] + red[2] + red[4] + red[6],
                                  red[1] + red[3] + red[5] + red[7]);
        if (tid < OO) woT[h * OO + tid] = w_out[tid * HH + h];
    } else {
        const int l = tid;
        if (l < 64) {
            for (int o = 0; o < OO; ++o) {
                float s = 0.f;
                #pragma unroll
                for (int c = 0; c < 4; ++c) s += w_out[o * HH + c * 64 + l];
                #pragma unroll
                for (int m = 32; m; m >>= 1) s += __shfl_xor(s, m, 64);
                if (l == 0) csum[o] = s;
            }
        }
    }
}

// Ballot-based active-feature compaction (256-thread blocks).
__device__ __forceinline__ int build_list(const float* __restrict__ xrow,
                                          int tid, int* __restrict__ xact,
                                          int* __restrict__ wcnt) {
    int lane = tid & 63, w = tid >> 6;
    float4 xv = make_float4(0.f, 0.f, 0.f, 0.f);
    if (tid < 175) xv = reinterpret_cast<const float4*>(xrow)[tid];
    unsigned long long b0 = __ballot(xv.x != 0.f);
    unsigned long long b1 = __ballot(xv.y != 0.f);
    unsigned long long b2 = __ballot(xv.z != 0.f);
    unsigned long long b3 = __ballot(xv.w != 0.f);
    int c0 = __popcll(b0), c1 = __popcll(b1), c2 = __popcll(b2), c3 = __popcll(b3);
    if (lane == 0) wcnt[w] = c0 + c1 + c2 + c3;
    __syncthreads();
    int base = 0;
    for (int i = 0; i < w; ++i) base += wcnt[i];
    int ntot = wcnt[0] + wcnt[1] + wcnt[2] + wcnt[3];
    unsigned long long below = (1ull << lane) - 1ull;
    if (xv.x != 0.f) xact[base + __popcll(b0 & below)] = 4 * tid + 0;
    if (xv.y != 0.f) xact[base + c0 + __popcll(b1 & below)] = 4 * tid + 1;
    if (xv.z != 0.f) xact[base + c0 + c1 + __popcll(b2 & below)] = 4 * tid + 2;
    if (xv.w != 0.f) xact[base + c0 + c1 + c2 + __popcll(b3 & below)] = 4 * tid + 3;
    int npad = (ntot + 7) & ~7;
    if (tid < npad - ntot) xact[ntot + tid] = FF;        // padding (guarded out)
    __syncthreads();
    return npad;
}

// blocks 0..255: exact fp32 t=0 drive -> spike row t=0 + per-b fallback flag.
// block 256: global fallback flag (induction premise: min rowsum_e > 0.04).
__global__ __launch_bounds__(256) void drive0_k(const float* __restrict__ x,
                                                const float* __restrict__ w_in,
                                                const float2* __restrict__ rsum,
                                                float* __restrict__ spk0,
                                                int* __restrict__ bflag,
                                                int* __restrict__ gflag) {
    const int b = blockIdx.x, tid = threadIdx.x;
    if (b == BB) {
        if (tid < 64) {
            float mn = 1e30f;
            #pragma unroll
            for (int c = 0; c < 4; ++c) mn = fminf(mn, rsum[c * 64 + tid].x);
            #pragma unroll
            for (int m = 32; m; m >>= 1) mn = fminf(mn, __shfl_xor(mn, m, 64));
            if (tid == 0) gflag[0] = (mn <= 0.04f) ? 1 : 0;
        }
        return;
    }
    __shared__ int xact[712];
    __shared__ int wcnt[4];
    __shared__ int nz;
    if (tid == 0) nz = 0;                    // visible after build_list's sync
    int npad = build_list(x + (size_t)b * TT * FF, tid, xact, wcnt);
    float ie = 0.f;
    for (int k = 0; k < npad; ++k) {
        int f = __builtin_amdgcn_readfirstlane(xact[k]);
        if (f < FF) {
            float w = w_in[tid * FF + f];
            ie += fmaxf(w, 0.f);
        }
    }
    float v0 = 0.5f * (ie * 60.f);           // reference association: DT*C_M_INV*(ge*(E-v))
    float z = (v0 - 1.f > 0.f) ? 1.f : 0.f;
    spk0[b * HH + tid] = z;
    if (z == 0.f) atomicAdd(&nz, 1);
    __syncthreads();
    if (tid == 0) bflag[b] = (nz != 0);
}

// Fused output writer.
// blocks [0, TT):   t = blk. Per-channel replay of the common-voltage scan up
//                   to t (bit-identical fp32 order to the reference scan), then
//                   broadcast the 20 values to all 256 batch rows.
// blocks [TT, ...): spike fill, 1.0f, one float4 per thread (262 MB coalesced).
__global__ __launch_bounds__(256) void fill_k(const float* __restrict__ csum,
                                              float* __restrict__ volt,
                                              float4* __restrict__ spk_t1) {
    const int blk = blockIdx.x, tid = threadIdx.x;
    if (blk < TT) {
        __shared__ float sm[OO];
        if (tid < OO) {
            const float cs = csum[tid];
            float vo = 0.f, io = 0.f;
            for (int k = 0; k <= blk; ++k) {
                vo = vo + 0.01f * (io - vo);             // old io (reference order)
                io = 0.98f * io + cs;                    // i_in == csum (all-fire)
            }
            sm[tid] = vo;
        }
        __syncthreads();
        float vv[OO];
        #pragma unroll
        for (int o = 0; o < OO; ++o) vv[o] = sm[o];      // thread-invariant
        float4* p = (float4*)(volt + ((size_t)blk * BB + tid) * OO);
        #pragma unroll
        for (int q = 0; q < 5; ++q)
            p[q] = make_float4(vv[4 * q], vv[4 * q + 1], vv[4 * q + 2], vv[4 * q + 3]);
    } else {
        long i = (long)(blk - TT) * 256 + tid;
        spk_t1[i] = make_float4(1.f, 1.f, 1.f, 1.f);
    }
}

// Exact sequential recompute for flagged batches only (normally exits at once).
__global__ __launch_bounds__(256) void fallback_k(
    const float* __restrict__ x, const float* __restrict__ w_in,
    const float2* __restrict__ wr2i, const float2* __restrict__ rsum,
    const float* __restrict__ woT, const float* __restrict__ csum,
    const int* __restrict__ gflag, const int* __restrict__ bflag,
    float* __restrict__ out) {
    const int b = blockIdx.x, tid = threadIdx.x;
    if ((gflag[0] | bflag[b]) == 0) return;              // uniform early exit

    const int w = tid >> 6, l = tid & 63;
    __shared__ int xact[712];
    __shared__ int wcnt[4];
    __shared__ unsigned long long mbuf[4];

    float* __restrict__ volt = out;                          // [T,B,O]
    float* __restrict__ spk  = out + (size_t)TT * BB * OO;   // [T,B,H]

    const float2 rs = rsum[tid];
    const float cs = (tid < OO) ? csum[tid] : 0.f;
    float ge = 0.f, gi = 0.f, v = 0.f, vo = 0.f, io = 0.f;
    unsigned long long mp0 = 0, mp1 = 0, mp2 = 0, mp3 = 0;

    for (int t = 0; t < TT; ++t) {
        int npad = build_list(x + ((size_t)b * TT + t) * FF, tid, xact, wcnt);
        float ie = 0.f, ii = 0.f;
        for (int k = 0; k < npad; ++k) {
            int f = __builtin_amdgcn_readfirstlane(xact[k]);
            if (f < FF) {
                float wv = w_in[tid * FF + f];
                ie += fmaxf(wv, 0.f);
                ii += fmaxf(-wv, 0.f);
            }
        }
        float ce, ci;
        if (t == 0) { ce = rs.x; ci = rs.y; }            // z_prev = 0 exactly
        else {
            ce = 0.f; ci = 0.f;
            if (mp0 | mp1 | mp2 | mp3) {
                unsigned long long mm;
                #pragma unroll
                for (int q = 0; q < 4; ++q) {
                    mm = (q == 0) ? mp0 : (q == 1) ? mp1 : (q == 2) ? mp2 : mp3;
                    while (mm) {
                        int i = __ffsll(mm) - 1; mm &= mm - 1;
                        float2 wv = wr2i[(size_t)(q * 64 + i) * HH + tid];
                        ce += wv.x; ci += wv.y;
                    }
                }
            }
        }
        ge = 0.98f * ge + ie + (rs.x - ce);
        gi = 0.99f * gi + ii + (rs.y - ci);
        v = v + 0.5f * (0.25f * (0.f - v) + ge * (60.f - v) + gi * (0.f - v));
        float z = (v - 1.f > 0.f) ? 1.f : 0.f;
        v *= (1.f - z);
        spk[((size_t)t * BB + b) * HH + tid] = z;

        unsigned long long nf = __ballot(z == 0.f);
        if (l == 0) mbuf[w] = nf;
        __syncthreads();
        mp0 = mbuf[0]; mp1 = mbuf[1]; mp2 = mbuf[2]; mp3 = mbuf[3];

        if (tid < OO) {
            float corr = 0.f;
            if (mp0 | mp1 | mp2 | mp3) {
                unsigned long long mm;
                mm = mp0; while (mm) { int i = __ffsll(mm) - 1; mm &= mm - 1; corr += woT[(0*64+i)*OO + tid]; }
                mm = mp1; while (mm) { int i = __ffsll(mm) - 1; mm &= mm - 1; corr += woT[(1*64+i)*OO + tid]; }
                mm = mp2; while (mm) { int i = __ffsll(mm) - 1; mm &= mm - 1; corr += woT[(2*64+i)*OO + tid]; }
                mm = mp3; while (mm) { int i = __ffsll(mm) - 1; mm &= mm - 1; corr += woT[(3*64+i)*OO + tid]; }
            }
            vo = vo + 0.01f * (io - vo);
            io = 0.98f * io + (cs - corr);
            volt[((size_t)t * BB + b) * OO + tid] = vo;
        }
    }
}

extern "C" void kernel_launch(void* const* d_in, const int* in_sizes, int n_in,
                              void* d_out, int out_size, void* d_ws, size_t ws_size,
                              hipStream_t stream) {
    (void)in_sizes; (void)n_in; (void)out_size; (void)ws_size;
    const float* x     = (const float*)d_in[0];
    const float* w_in  = (const float*)d_in[1];
    const float* w_rec = (const float*)d_in[2];
    const float* w_out = (const float*)d_in[3];
    float* out = (float*)d_out;

    char* ws = (char*)d_ws;
    float2* wr2i  = (float2*)(ws + WS_WRT);
    float2* rsum  = (float2*)(ws + WS_RSUM);
    float*  woT   = (float*) (ws + WS_WOT);
    float*  csum  = (float*) (ws + WS_CSUM);
    int*    gflag = (int*)   (ws + WS_GFLAG);
    int*    bflag = (int*)   (ws + WS_BFLAG);

    float* volt = out;                                   // [T,B,O]
    float* spk  = out + (size_t)TT * BB * OO;            // [T,B,H]
    float4* spk_t1 = (float4*)(spk + (size_t)BB * HH);   // t>=1 region (16B-aligned)
    const long nblk_spk = (long)(TT - 1) * BB * HH / 4 / 256;   // 63936, exact

    hipLaunchKernelGGL(prep_k,     dim3(HH + 1),           dim3(256), 0, stream,
                       w_rec, w_out, wr2i, rsum, woT, csum);
    hipLaunchKernelGGL(drive0_k,   dim3(BB + 1),           dim3(256), 0, stream,
                       x, w_in, rsum, spk, bflag, gflag);
    hipLaunchKernelGGL(fill_k,     dim3(TT + (int)nblk_spk), dim3(256), 0, stream,
                       csum, volt, spk_t1);
    hipLaunchKernelGGL(fallback_k, dim3(BB),               dim3(256), 0, stream,
                       x, w_in, wr2i, rsum, woT, csum, gflag, bflag, out);
}